// Round 1
// baseline (763.843 us; speedup 1.0000x reference)
//
#include <hip/hip_runtime.h>
#include <hip/hip_bf16.h>

#define N_NODES 100000
#define E_EDGES 640000
// channel widths: IN 256, HID 128, OUT 64+64

// ---------------- workspace layout (bytes) ----------------
#define WS_HIST    0          // int[100000]
#define WS_CURSOR  524288     // int[100000]
#define WS_OFFS    1048576    // int[100000]
#define WS_DINV    1572864    // float[100000]
#define WS_BSUMS   2097152    // int[256]
#define WS_ESRC    2621440    // int[640000]
#define WS_H0      5242880    // float[100000*128] (also reused as g after agg1)
#define WS_H       56442880   // float[100000*128]
// total: 107,642,880 bytes

// ---------------- small setup kernels ----------------
__global__ __launch_bounds__(256) void k_init(int* __restrict__ hist, int* __restrict__ cursor) {
    int i = blockIdx.x * 256 + threadIdx.x;
    if (i < N_NODES) { hist[i] = 0; cursor[i] = 0; }
}

__global__ __launch_bounds__(256) void k_hist(const int* __restrict__ dst, int* __restrict__ hist) {
    int e = blockIdx.x * 256 + threadIdx.x;
    if (e < E_EDGES) atomicAdd(&hist[dst[e]], 1);
}

__global__ __launch_bounds__(256) void k_dinv(const int* __restrict__ hist, float* __restrict__ dinv) {
    int i = blockIdx.x * 256 + threadIdx.x;
    if (i < N_NODES) dinv[i] = rsqrtf((float)(hist[i] + 1));   // +1 self-loop
}

// exclusive scan, level 1: 1024 elements per 256-thread block
__global__ __launch_bounds__(256) void k_scan1(const int* __restrict__ hist,
                                               int* __restrict__ offs,
                                               int* __restrict__ bsums) {
    __shared__ int sd[256];
    int t = threadIdx.x;
    int base = blockIdx.x * 1024 + t * 4;
    int v[4];
#pragma unroll
    for (int j = 0; j < 4; ++j) v[j] = (base + j < N_NODES) ? hist[base + j] : 0;
    int s = v[0] + v[1] + v[2] + v[3];
    sd[t] = s;
    __syncthreads();
    for (int d = 1; d < 256; d <<= 1) {
        int x = (t >= d) ? sd[t - d] : 0;
        __syncthreads();
        sd[t] += x;
        __syncthreads();
    }
    int excl = sd[t] - s;
    if (t == 255) bsums[blockIdx.x] = sd[255];
    int run = excl;
#pragma unroll
    for (int j = 0; j < 4; ++j) {
        if (base + j < N_NODES) offs[base + j] = run;
        run += v[j];
    }
}

// level 2: exclusive scan of the (<=128) block sums, single block
__global__ __launch_bounds__(128) void k_scan2(int* __restrict__ bsums, int nb) {
    __shared__ int sd[128];
    int t = threadIdx.x;
    int v = (t < nb) ? bsums[t] : 0;
    sd[t] = v;
    __syncthreads();
    for (int d = 1; d < 128; d <<= 1) {
        int x = (t >= d) ? sd[t - d] : 0;
        __syncthreads();
        sd[t] += x;
        __syncthreads();
    }
    if (t < nb) bsums[t] = sd[t] - v;
}

// level 3: add block offsets
__global__ __launch_bounds__(256) void k_scan3(int* __restrict__ offs, const int* __restrict__ bsums) {
    int i = blockIdx.x * 256 + threadIdx.x;
    if (i < N_NODES) offs[i] += bsums[i >> 10];
}

// CSR fill: place each edge's src into the dst bucket
__global__ __launch_bounds__(256) void k_fill(const int* __restrict__ src, const int* __restrict__ dst,
                                              const int* __restrict__ offs, int* __restrict__ cursor,
                                              int* __restrict__ esrc) {
    int e = blockIdx.x * 256 + threadIdx.x;
    if (e < E_EDGES) {
        int d = dst[e];
        int p = offs[d] + atomicAdd(&cursor[d], 1);
        esrc[p] = src[e];
    }
}

// ---------------- tiled fp32 GEMM ----------------
// A [N][K] @ B [K][128] -> 128x128 tile per block, 8x8 per thread, TK=16
// MODE 0: out[N][128], no bias (B0 = W1 [K][128])
// MODE 1: B0=W_mu [K][64], B1=W_logvar [K][64]; out = d_out (mu at 0, logvar at N*64), + biases
template <int K, int MODE>
__global__ __launch_bounds__(256) void k_gemm(const float* __restrict__ A,
                                              const float* __restrict__ B0,
                                              const float* __restrict__ B1,
                                              const float* __restrict__ bias0,
                                              const float* __restrict__ bias1,
                                              float* __restrict__ out) {
    __shared__ float As[16][132];   // [kk][row], pad 132: 16B-aligned rows, <=2-way store conflicts
    __shared__ float Bs[16][128];   // [kk][col]
    int tid = threadIdx.x;
    int row0 = blockIdx.x * 128;
    int tx = tid & 15;         // col group (8 cols)
    int ty = tid >> 4;         // row group (8 rows)
    float acc[8][8];
#pragma unroll
    for (int i = 0; i < 8; ++i)
#pragma unroll
        for (int j = 0; j < 8; ++j) acc[i][j] = 0.f;

    int lkk = tid & 15;        // As loader: kk
    int lrr = tid >> 4;        // As loader: row base (0..15)
    int lc  = tid & 127;       // Bs loader: col
    int lkg = tid >> 7;        // Bs loader: kk base (0..1)

    for (int k0 = 0; k0 < K; k0 += 16) {
#pragma unroll
        for (int p = 0; p < 8; ++p) {
            int r = lrr + p * 16;
            int row = row0 + r;
            As[lkk][r] = (row < N_NODES) ? A[(size_t)row * K + k0 + lkk] : 0.f;
        }
#pragma unroll
        for (int p = 0; p < 8; ++p) {
            int kk = lkg + p * 2;
            float w;
            if (MODE == 0) w = B0[(size_t)(k0 + kk) * 128 + lc];
            else w = (lc < 64) ? B0[(size_t)(k0 + kk) * 64 + lc]
                               : B1[(size_t)(k0 + kk) * 64 + (lc - 64)];
            Bs[kk][lc] = w;
        }
        __syncthreads();
#pragma unroll
        for (int kk = 0; kk < 16; ++kk) {
            float a[8], b[8];
#pragma unroll
            for (int i = 0; i < 8; ++i) a[i] = As[kk][ty * 8 + i];
#pragma unroll
            for (int j = 0; j < 8; ++j) b[j] = Bs[kk][tx * 8 + j];
#pragma unroll
            for (int i = 0; i < 8; ++i)
#pragma unroll
                for (int j = 0; j < 8; ++j) acc[i][j] += a[i] * b[j];
        }
        __syncthreads();
    }

#pragma unroll
    for (int i = 0; i < 8; ++i) {
        int row = row0 + ty * 8 + i;
        if (row >= N_NODES) continue;
#pragma unroll
        for (int j = 0; j < 8; ++j) {
            int cc = tx * 8 + j;
            if (MODE == 0) {
                out[(size_t)row * 128 + cc] = acc[i][j];
            } else {
                if (cc < 64) out[(size_t)row * 64 + cc] = acc[i][j] + bias0[cc];
                else out[(size_t)N_NODES * 64 + (size_t)row * 64 + (cc - 64)] = acc[i][j] + bias1[cc - 64];
            }
        }
    }
}

// ---------------- CSR aggregation: one wave per node, 128 channels as float2/lane ----------------
// out[i] = (BIAS? b : 0) + dinv[i]^2 * f(in[i]) + sum_edges dinv[s]*dinv[i] * f(in[s]),  f = relu if RELU
template <bool RELU, bool BIAS>
__global__ __launch_bounds__(256) void k_agg(const float2* __restrict__ in,
                                             float2* __restrict__ out,
                                             const float* __restrict__ dinv,
                                             const int* __restrict__ esrc,
                                             const int* __restrict__ offs,
                                             const int* __restrict__ cnt,
                                             const float2* __restrict__ bias) {
    int wid = (blockIdx.x * 256 + threadIdx.x) >> 6;   // node id, one wave per node
    if (wid >= N_NODES) return;
    int l = threadIdx.x & 63;                          // channel pair
    float di = dinv[wid];
    float2 v = in[(size_t)wid * 64 + l];
    if (RELU) { v.x = fmaxf(v.x, 0.f); v.y = fmaxf(v.y, 0.f); }
    float s2 = di * di;
    float2 acc;
    acc.x = s2 * v.x;
    acc.y = s2 * v.y;
    if (BIAS) {
        float2 b = bias[l];
        acc.x += b.x;
        acc.y += b.y;
    }
    int start = offs[wid];
    int n = cnt[wid];
    for (int e = 0; e < n; ++e) {
        int s = esrc[start + e];
        float w = dinv[s] * di;
        float2 u = in[(size_t)s * 64 + l];
        if (RELU) { u.x = fmaxf(u.x, 0.f); u.y = fmaxf(u.y, 0.f); }
        acc.x += w * u.x;
        acc.y += w * u.y;
    }
    out[(size_t)wid * 64 + l] = acc;
}

// ---------------- launch ----------------
extern "C" void kernel_launch(void* const* d_in, const int* in_sizes, int n_in,
                              void* d_out, int out_size, void* d_ws, size_t ws_size,
                              hipStream_t stream) {
    const float* x    = (const float*)d_in[0];
    const int*   ei   = (const int*)d_in[1];      // [2][E]: row0 src, row1 dst
    const float* W1   = (const float*)d_in[2];
    const float* b1   = (const float*)d_in[3];
    const float* Wmu  = (const float*)d_in[4];
    const float* bmu  = (const float*)d_in[5];
    const float* Wlv  = (const float*)d_in[6];
    const float* blv  = (const float*)d_in[7];
    float* outp = (float*)d_out;

    const int* src = ei;
    const int* dst = ei + E_EDGES;

    char* ws = (char*)d_ws;
    int*   hist   = (int*)(ws + WS_HIST);
    int*   cursor = (int*)(ws + WS_CURSOR);
    int*   offs   = (int*)(ws + WS_OFFS);
    float* dinv   = (float*)(ws + WS_DINV);
    int*   bsums  = (int*)(ws + WS_BSUMS);
    int*   esrc   = (int*)(ws + WS_ESRC);
    float* h0     = (float*)(ws + WS_H0);     // x@W1, later reused as g
    float* h      = (float*)(ws + WS_H);      // pre-relu hidden (bias applied)

    const int NB_N = (N_NODES + 255) / 256;      // 391
    const int NB_E = (E_EDGES + 255) / 256;      // 2500
    const int NB_S = (N_NODES + 1023) / 1024;    // 98

    // degree + CSR build
    k_init<<<NB_N, 256, 0, stream>>>(hist, cursor);
    k_hist<<<NB_E, 256, 0, stream>>>(dst, hist);
    k_dinv<<<NB_N, 256, 0, stream>>>(hist, dinv);
    k_scan1<<<NB_S, 256, 0, stream>>>(hist, offs, bsums);
    k_scan2<<<1, 128, 0, stream>>>(bsums, NB_S);
    k_scan3<<<NB_N, 256, 0, stream>>>(offs, bsums);
    k_fill<<<NB_E, 256, 0, stream>>>(src, dst, offs, cursor, esrc);

    // layer 1: h0 = x @ W1 ; h = A_hat h0 + b1 (relu deferred to readers)
    k_gemm<256, 0><<<(N_NODES + 127) / 128, 256, 0, stream>>>(x, W1, nullptr, nullptr, nullptr, h0);
    k_agg<false, true><<<(N_NODES * 64 + 255) / 256, 256, 0, stream>>>(
        (const float2*)h0, (float2*)h, dinv, esrc, offs, hist, (const float2*)b1);

    // layer 2+3: g = A_hat relu(h) ; [mu|logvar] = g @ [Wmu|Wlv] + [bmu|blv]
    k_agg<true, false><<<(N_NODES * 64 + 255) / 256, 256, 0, stream>>>(
        (const float2*)h, (float2*)h0, dinv, esrc, offs, hist, nullptr);
    k_gemm<128, 1><<<(N_NODES + 127) / 128, 256, 0, stream>>>(h0, Wmu, Wlv, bmu, blv, outp);
}

// Round 2
// 433.145 us; speedup vs baseline: 1.7635x; 1.7635x over previous
//
#include <hip/hip_runtime.h>
#include <hip/hip_bf16.h>

#define N_NODES 100000
#define E_EDGES 640000
// channels: IN 256, HID 128, OUT 64+64

typedef __attribute__((ext_vector_type(8))) short short8;
typedef __attribute__((ext_vector_type(4))) float float4v;

__device__ __forceinline__ float bf2f(unsigned int u16) {
    union { unsigned int i; float f; } c; c.i = u16 << 16; return c.f;
}
__device__ __forceinline__ unsigned short f2bf(float f) {
    union { float f; unsigned int i; } c; c.f = f;
    unsigned int x = c.i;
    unsigned int r = (x + 0x7fffu + ((x >> 16) & 1u)) >> 16;   // RNE
    return (unsigned short)r;
}

// ---------------- workspace layout (bytes) ----------------
#define WS_HIST    0          // int[100000]
#define WS_CURSOR  524288     // int[100000]
#define WS_OFFS    1048576    // int[100000]
#define WS_DINV    1572864    // float[100000]
#define WS_BSUMS   2097152    // int[256]
#define WS_ESRC    2621440    // int[640000]
#define WS_WP1     5242880    // bf16[128][256] packed W1^T
#define WS_WP2     5373952    // bf16[128][128] packed [Wmu|Wlv]^T
#define WS_H0      5767168    // bf16[100000*128]  (x@W1, later reused as g)
#define WS_H       31457280   // bf16[100000*128]  (pre-relu hidden, bias applied)
// total ~57.1 MB

// ---------------- setup kernels ----------------
__global__ __launch_bounds__(256) void k_init(int* __restrict__ hist, int* __restrict__ cursor) {
    int i = blockIdx.x * 256 + threadIdx.x;
    if (i < N_NODES) { hist[i] = 0; cursor[i] = 0; }
}

__global__ __launch_bounds__(256) void k_hist(const int* __restrict__ dst, int* __restrict__ hist) {
    int e = blockIdx.x * 256 + threadIdx.x;
    if (e < E_EDGES) atomicAdd(&hist[dst[e]], 1);
}

__global__ __launch_bounds__(256) void k_dinv(const int* __restrict__ hist, float* __restrict__ dinv) {
    int i = blockIdx.x * 256 + threadIdx.x;
    if (i < N_NODES) dinv[i] = rsqrtf((float)(hist[i] + 1));
}

__global__ __launch_bounds__(256) void k_scan1(const int* __restrict__ hist,
                                               int* __restrict__ offs,
                                               int* __restrict__ bsums) {
    __shared__ int sd[256];
    int t = threadIdx.x;
    int base = blockIdx.x * 1024 + t * 4;
    int v[4];
#pragma unroll
    for (int j = 0; j < 4; ++j) v[j] = (base + j < N_NODES) ? hist[base + j] : 0;
    int s = v[0] + v[1] + v[2] + v[3];
    sd[t] = s;
    __syncthreads();
    for (int d = 1; d < 256; d <<= 1) {
        int x = (t >= d) ? sd[t - d] : 0;
        __syncthreads();
        sd[t] += x;
        __syncthreads();
    }
    int excl = sd[t] - s;
    if (t == 255) bsums[blockIdx.x] = sd[255];
    int run = excl;
#pragma unroll
    for (int j = 0; j < 4; ++j) {
        if (base + j < N_NODES) offs[base + j] = run;
        run += v[j];
    }
}

__global__ __launch_bounds__(128) void k_scan2(int* __restrict__ bsums, int nb) {
    __shared__ int sd[128];
    int t = threadIdx.x;
    int v = (t < nb) ? bsums[t] : 0;
    sd[t] = v;
    __syncthreads();
    for (int d = 1; d < 128; d <<= 1) {
        int x = (t >= d) ? sd[t - d] : 0;
        __syncthreads();
        sd[t] += x;
        __syncthreads();
    }
    if (t < nb) bsums[t] = sd[t] - v;
}

__global__ __launch_bounds__(256) void k_scan3(int* __restrict__ offs, const int* __restrict__ bsums) {
    int i = blockIdx.x * 256 + threadIdx.x;
    if (i < N_NODES) offs[i] += bsums[i >> 10];
}

__global__ __launch_bounds__(256) void k_fill(const int* __restrict__ src, const int* __restrict__ dst,
                                              const int* __restrict__ offs, int* __restrict__ cursor,
                                              int* __restrict__ esrc) {
    int e = blockIdx.x * 256 + threadIdx.x;
    if (e < E_EDGES) {
        int d = dst[e];
        int p = offs[d] + atomicAdd(&cursor[d], 1);
        esrc[p] = src[e];
    }
}

// pack weights to bf16 [n][k] (B^T) layout; W2 = [Wmu | Wlv] columns
__global__ __launch_bounds__(256) void k_pack(const float* __restrict__ W1,
                                              const float* __restrict__ Wmu,
                                              const float* __restrict__ Wlv,
                                              unsigned short* __restrict__ Wp1,
                                              unsigned short* __restrict__ Wp2) {
    int i = blockIdx.x * 256 + threadIdx.x;
    if (i < 256 * 128) {
        int k = i >> 7, n = i & 127;
        Wp1[n * 256 + k] = f2bf(W1[i]);
    }
    if (i < 128 * 128) {
        int k = i >> 7, n = i & 127;
        float w = (n < 64) ? Wmu[k * 64 + n] : Wlv[k * 64 + (n - 64)];
        Wp2[n * 128 + k] = f2bf(w);
    }
}

// ---------------- bf16 MFMA GEMM ----------------
// C[N][128] = A[N][K] @ B[K][128]; B pre-packed as Bpack[n][k] bf16.
// 128x128 tile/block, 4 waves, each wave 64x64 via 4x4 of 16x16x32 MFMA.
// AFP32: A is fp32 (convert in staging) else bf16.
// MODE 0: write bf16 out[N][128].  MODE 1: fp32 d_out split mu/logvar + bias.
template <int K, int AFP32, int MODE>
__global__ __launch_bounds__(256) void k_mgemm(const void* __restrict__ Ap,
                                               const unsigned short* __restrict__ Bpack,
                                               const float* __restrict__ bias0,
                                               const float* __restrict__ bias1,
                                               void* __restrict__ outp) {
    constexpr int LDT = 40;  // padded LDS row stride in bf16 (80 B): 2-way max bank aliasing
    __shared__ unsigned short As[128 * LDT];
    __shared__ unsigned short Bs[128 * LDT];
    int tid = threadIdx.x;
    int row0 = blockIdx.x * 128;
    int wave = tid >> 6, lane = tid & 63;
    int c = lane & 15, q = lane >> 4;
    int wrow = (wave >> 1) * 64, wcol = (wave & 1) * 64;

    float4v acc[4][4];
#pragma unroll
    for (int i = 0; i < 4; ++i)
#pragma unroll
        for (int j = 0; j < 4; ++j) acc[i][j] = (float4v){0.f, 0.f, 0.f, 0.f};

    int srow = tid >> 1;          // staging row 0..127
    int shalf = (tid & 1) * 16;   // staging col half: 0 or 16
    const short8 zed = {0, 0, 0, 0, 0, 0, 0, 0};

    for (int k0 = 0; k0 < K; k0 += 32) {
        // ---- stage B tile: Bs[n][kk] = Bpack[n][k0+kk]
        {
            const unsigned short* src = Bpack + (size_t)srow * K + k0 + shalf;
            short8 b0 = *(const short8*)(src);
            short8 b1 = *(const short8*)(src + 8);
            *(short8*)(&Bs[srow * LDT + shalf])     = b0;
            *(short8*)(&Bs[srow * LDT + shalf + 8]) = b1;
        }
        // ---- stage A tile: As[r][kk] = bf16(A[row0+r][k0+kk])
        {
            int grow = row0 + srow;
            short8 a0 = zed, a1 = zed;
            if (AFP32) {
                if (grow < N_NODES) {
                    const float* src = (const float*)Ap + (size_t)grow * K + k0 + shalf;
                    float4v f0 = *(const float4v*)(src);
                    float4v f1 = *(const float4v*)(src + 4);
                    float4v f2 = *(const float4v*)(src + 8);
                    float4v f3 = *(const float4v*)(src + 12);
                    unsigned short t[16];
#pragma unroll
                    for (int j = 0; j < 4; ++j) t[j]      = f2bf(f0[j]);
#pragma unroll
                    for (int j = 0; j < 4; ++j) t[4 + j]  = f2bf(f1[j]);
#pragma unroll
                    for (int j = 0; j < 4; ++j) t[8 + j]  = f2bf(f2[j]);
#pragma unroll
                    for (int j = 0; j < 4; ++j) t[12 + j] = f2bf(f3[j]);
#pragma unroll
                    for (int j = 0; j < 8; ++j) a0[j] = (short)t[j];
#pragma unroll
                    for (int j = 0; j < 8; ++j) a1[j] = (short)t[8 + j];
                }
            } else {
                if (grow < N_NODES) {
                    const unsigned short* src = (const unsigned short*)Ap + (size_t)grow * K + k0 + shalf;
                    a0 = *(const short8*)(src);
                    a1 = *(const short8*)(src + 8);
                }
            }
            *(short8*)(&As[srow * LDT + shalf])     = a0;
            *(short8*)(&As[srow * LDT + shalf + 8]) = a1;
        }
        __syncthreads();

        // ---- fragments + MFMA
        short8 af[4], bfr[4];
#pragma unroll
        for (int mt = 0; mt < 4; ++mt)
            af[mt] = *(const short8*)(&As[(wrow + mt * 16 + c) * LDT + q * 8]);
#pragma unroll
        for (int nt = 0; nt < 4; ++nt)
            bfr[nt] = *(const short8*)(&Bs[(wcol + nt * 16 + c) * LDT + q * 8]);
#pragma unroll
        for (int mt = 0; mt < 4; ++mt)
#pragma unroll
            for (int nt = 0; nt < 4; ++nt)
                acc[mt][nt] = __builtin_amdgcn_mfma_f32_16x16x32_bf16(af[mt], bfr[nt], acc[mt][nt], 0, 0, 0);
        __syncthreads();
    }

    // ---- epilogue.  D: col = lane&15, row = q*4 + reg
#pragma unroll
    for (int mt = 0; mt < 4; ++mt) {
#pragma unroll
        for (int i = 0; i < 4; ++i) {
            int row = row0 + wrow + mt * 16 + q * 4 + i;
            if (row >= N_NODES) continue;
#pragma unroll
            for (int nt = 0; nt < 4; ++nt) {
                int cc = wcol + nt * 16 + c;
                float v = acc[mt][nt][i];
                if (MODE == 0) {
                    ((unsigned short*)outp)[(size_t)row * 128 + cc] = f2bf(v);
                } else {
                    float* o = (float*)outp;
                    if (cc < 64) o[(size_t)row * 64 + cc] = v + bias0[cc];
                    else o[(size_t)N_NODES * 64 + (size_t)row * 64 + (cc - 64)] = v + bias1[cc - 64];
                }
            }
        }
    }
}

// ---------------- CSR aggregation, bf16 in/out, fp32 accumulate ----------------
// one wave per node; lane l handles channels {2l, 2l+1} packed in one uint
template <bool RELU, bool BIAS>
__global__ __launch_bounds__(256) void k_agg(const unsigned int* __restrict__ in,
                                             unsigned int* __restrict__ out,
                                             const float* __restrict__ dinv,
                                             const int* __restrict__ esrc,
                                             const int* __restrict__ offs,
                                             const int* __restrict__ cnt,
                                             const float* __restrict__ bias) {
    int wid = (blockIdx.x * 256 + threadIdx.x) >> 6;
    if (wid >= N_NODES) return;
    int l = threadIdx.x & 63;
    float di = dinv[wid];
    unsigned int u = in[(size_t)wid * 64 + l];
    float vx = bf2f(u & 0xffffu), vy = bf2f(u >> 16);
    if (RELU) { vx = fmaxf(vx, 0.f); vy = fmaxf(vy, 0.f); }
    float s2 = di * di;
    float ax = s2 * vx, ay = s2 * vy;
    if (BIAS) { ax += bias[2 * l]; ay += bias[2 * l + 1]; }
    int start = offs[wid];
    int n = cnt[wid];
    for (int e = 0; e < n; ++e) {
        int s = esrc[start + e];
        float w = dinv[s] * di;
        unsigned int us = in[(size_t)s * 64 + l];
        float ux = bf2f(us & 0xffffu), uy = bf2f(us >> 16);
        if (RELU) { ux = fmaxf(ux, 0.f); uy = fmaxf(uy, 0.f); }
        ax += w * ux;
        ay += w * uy;
    }
    out[(size_t)wid * 64 + l] = (unsigned int)f2bf(ax) | ((unsigned int)f2bf(ay) << 16);
}

// ---------------- launch ----------------
extern "C" void kernel_launch(void* const* d_in, const int* in_sizes, int n_in,
                              void* d_out, int out_size, void* d_ws, size_t ws_size,
                              hipStream_t stream) {
    const float* x    = (const float*)d_in[0];
    const int*   ei   = (const int*)d_in[1];
    const float* W1   = (const float*)d_in[2];
    const float* b1   = (const float*)d_in[3];
    const float* Wmu  = (const float*)d_in[4];
    const float* bmu  = (const float*)d_in[5];
    const float* Wlv  = (const float*)d_in[6];
    const float* blv  = (const float*)d_in[7];
    float* outp = (float*)d_out;

    const int* src = ei;
    const int* dst = ei + E_EDGES;

    char* ws = (char*)d_ws;
    int*            hist   = (int*)(ws + WS_HIST);
    int*            cursor = (int*)(ws + WS_CURSOR);
    int*            offs   = (int*)(ws + WS_OFFS);
    float*          dinv   = (float*)(ws + WS_DINV);
    int*            bsums  = (int*)(ws + WS_BSUMS);
    int*            esrc   = (int*)(ws + WS_ESRC);
    unsigned short* Wp1    = (unsigned short*)(ws + WS_WP1);
    unsigned short* Wp2    = (unsigned short*)(ws + WS_WP2);
    unsigned short* h0     = (unsigned short*)(ws + WS_H0);   // x@W1 bf16, reused as g
    unsigned short* h      = (unsigned short*)(ws + WS_H);    // hidden bf16 (bias applied, pre-relu)

    const int NB_N = (N_NODES + 255) / 256;
    const int NB_E = (E_EDGES + 255) / 256;
    const int NB_S = (N_NODES + 1023) / 1024;
    const int NB_G = (N_NODES + 127) / 128;

    // degree + CSR build + weight packing
    k_init<<<NB_N, 256, 0, stream>>>(hist, cursor);
    k_hist<<<NB_E, 256, 0, stream>>>(dst, hist);
    k_dinv<<<NB_N, 256, 0, stream>>>(hist, dinv);
    k_scan1<<<NB_S, 256, 0, stream>>>(hist, offs, bsums);
    k_scan2<<<1, 128, 0, stream>>>(bsums, NB_S);
    k_scan3<<<NB_N, 256, 0, stream>>>(offs, bsums);
    k_fill<<<NB_E, 256, 0, stream>>>(src, dst, offs, cursor, esrc);
    k_pack<<<128, 256, 0, stream>>>(W1, Wmu, Wlv, Wp1, Wp2);

    // layer 1: h0 = bf16(x) @ W1 (MFMA) ; h = A_hat h0 + b1
    k_mgemm<256, 1, 0><<<NB_G, 256, 0, stream>>>(x, Wp1, nullptr, nullptr, h0);
    k_agg<false, true><<<(N_NODES * 64 + 255) / 256, 256, 0, stream>>>(
        (const unsigned int*)h0, (unsigned int*)h, dinv, esrc, offs, hist, b1);

    // layer 2+3: g = A_hat relu(h) ; [mu|logvar] = g @ [Wmu|Wlv] + bias
    k_agg<true, false><<<(N_NODES * 64 + 255) / 256, 256, 0, stream>>>(
        (const unsigned int*)h, (unsigned int*)h0, dinv, esrc, offs, hist, nullptr);
    k_mgemm<128, 0, 1><<<NB_G, 256, 0, stream>>>(h0, Wp2, bmu, blv, outp);
}

// Round 3
// 368.192 us; speedup vs baseline: 2.0746x; 1.1764x over previous
//
#include <hip/hip_runtime.h>
#include <hip/hip_bf16.h>

#define N_NODES 100000
#define E_EDGES 640000
// channels: IN 256, HID 128, OUT 64+64

typedef __attribute__((ext_vector_type(8))) short short8;
typedef __attribute__((ext_vector_type(4))) float float4v;

__device__ __forceinline__ float bf2f(unsigned int u16) {
    union { unsigned int i; float f; } c; c.i = u16 << 16; return c.f;
}
__device__ __forceinline__ unsigned short f2bf(float f) {
    union { float f; unsigned int i; } c; c.f = f;
    unsigned int x = c.i;
    unsigned int r = (x + 0x7fffu + ((x >> 16) & 1u)) >> 16;   // RNE
    return (unsigned short)r;
}

// ---------------- workspace layout (bytes) ----------------
#define WS_HIST    0          // int[100000]
#define WS_CURSOR  524288     // int[100000]
#define WS_OFFS    1048576    // int[100000]
#define WS_DINV    1572864    // float[100000]
#define WS_BSUMS   2097152    // int[256]
#define WS_ESRC    2621440    // int[640000]
#define WS_EW      5242880    // float[640000] per-edge weight dinv[s]*dinv[d]
#define WS_WP1     7864320    // bf16[128][256] packed W1^T
#define WS_WP2     7995392    // bf16[128][128] packed [Wmu|Wlv]^T
#define WS_H0      8388608    // bf16[100000*128]  (x@W1, later reused as g)
#define WS_H       34603008   // bf16[100000*128]  (pre-relu hidden, bias applied)
// total ~60.3 MB

// ---------------- setup kernels ----------------
__global__ __launch_bounds__(256) void k_init(int* __restrict__ hist, int* __restrict__ cursor) {
    int i = blockIdx.x * 256 + threadIdx.x;
    if (i < N_NODES) { hist[i] = 0; cursor[i] = 0; }
}

__global__ __launch_bounds__(256) void k_hist(const int* __restrict__ dst, int* __restrict__ hist) {
    int e = blockIdx.x * 256 + threadIdx.x;
    if (e < E_EDGES) atomicAdd(&hist[dst[e]], 1);
}

__global__ __launch_bounds__(256) void k_dinv(const int* __restrict__ hist, float* __restrict__ dinv) {
    int i = blockIdx.x * 256 + threadIdx.x;
    if (i < N_NODES) dinv[i] = rsqrtf((float)(hist[i] + 1));
}

__global__ __launch_bounds__(256) void k_scan1(const int* __restrict__ hist,
                                               int* __restrict__ offs,
                                               int* __restrict__ bsums) {
    __shared__ int sd[256];
    int t = threadIdx.x;
    int base = blockIdx.x * 1024 + t * 4;
    int v[4];
#pragma unroll
    for (int j = 0; j < 4; ++j) v[j] = (base + j < N_NODES) ? hist[base + j] : 0;
    int s = v[0] + v[1] + v[2] + v[3];
    sd[t] = s;
    __syncthreads();
    for (int d = 1; d < 256; d <<= 1) {
        int x = (t >= d) ? sd[t - d] : 0;
        __syncthreads();
        sd[t] += x;
        __syncthreads();
    }
    int excl = sd[t] - s;
    if (t == 255) bsums[blockIdx.x] = sd[255];
    int run = excl;
#pragma unroll
    for (int j = 0; j < 4; ++j) {
        if (base + j < N_NODES) offs[base + j] = run;
        run += v[j];
    }
}

__global__ __launch_bounds__(128) void k_scan2(int* __restrict__ bsums, int nb) {
    __shared__ int sd[128];
    int t = threadIdx.x;
    int v = (t < nb) ? bsums[t] : 0;
    sd[t] = v;
    __syncthreads();
    for (int d = 1; d < 128; d <<= 1) {
        int x = (t >= d) ? sd[t - d] : 0;
        __syncthreads();
        sd[t] += x;
        __syncthreads();
    }
    if (t < nb) bsums[t] = sd[t] - v;
}

__global__ __launch_bounds__(256) void k_scan3(int* __restrict__ offs, const int* __restrict__ bsums) {
    int i = blockIdx.x * 256 + threadIdx.x;
    if (i < N_NODES) offs[i] += bsums[i >> 10];
}

// CSR fill + per-edge weight
__global__ __launch_bounds__(256) void k_fill(const int* __restrict__ src, const int* __restrict__ dst,
                                              const int* __restrict__ offs, int* __restrict__ cursor,
                                              const float* __restrict__ dinv,
                                              int* __restrict__ esrc, float* __restrict__ ew) {
    int e = blockIdx.x * 256 + threadIdx.x;
    if (e < E_EDGES) {
        int s = src[e], d = dst[e];
        int p = offs[d] + atomicAdd(&cursor[d], 1);
        esrc[p] = s;
        ew[p] = dinv[s] * dinv[d];
    }
}

// pack weights to bf16 [n][k] (B^T) layout; W2 = [Wmu | Wlv] columns
__global__ __launch_bounds__(256) void k_pack(const float* __restrict__ W1,
                                              const float* __restrict__ Wmu,
                                              const float* __restrict__ Wlv,
                                              unsigned short* __restrict__ Wp1,
                                              unsigned short* __restrict__ Wp2) {
    int i = blockIdx.x * 256 + threadIdx.x;
    if (i < 256 * 128) {
        int k = i >> 7, n = i & 127;
        Wp1[n * 256 + k] = f2bf(W1[i]);
    }
    if (i < 128 * 128) {
        int k = i >> 7, n = i & 127;
        float w = (n < 64) ? Wmu[k * 64 + n] : Wlv[k * 64 + (n - 64)];
        Wp2[n * 128 + k] = f2bf(w);
    }
}

// ---------------- bf16 MFMA GEMM ----------------
// C[N][128] = A[N][K] @ B[K][128]; B pre-packed as Bpack[n][k] bf16.
// 128x128 tile/block, 4 waves, each wave 64x64 via 4x4 of 16x16x32 MFMA.
template <int K, int AFP32, int MODE>
__global__ __launch_bounds__(256) void k_mgemm(const void* __restrict__ Ap,
                                               const unsigned short* __restrict__ Bpack,
                                               const float* __restrict__ bias0,
                                               const float* __restrict__ bias1,
                                               void* __restrict__ outp) {
    constexpr int LDT = 40;  // padded LDS row stride in bf16 (80 B)
    __shared__ unsigned short As[128 * LDT];
    __shared__ unsigned short Bs[128 * LDT];
    int tid = threadIdx.x;
    int row0 = blockIdx.x * 128;
    int wave = tid >> 6, lane = tid & 63;
    int c = lane & 15, q = lane >> 4;
    int wrow = (wave >> 1) * 64, wcol = (wave & 1) * 64;

    float4v acc[4][4];
#pragma unroll
    for (int i = 0; i < 4; ++i)
#pragma unroll
        for (int j = 0; j < 4; ++j) acc[i][j] = (float4v){0.f, 0.f, 0.f, 0.f};

    int srow = tid >> 1;          // staging row 0..127
    int shalf = (tid & 1) * 16;   // staging col half
    const short8 zed = {0, 0, 0, 0, 0, 0, 0, 0};

    for (int k0 = 0; k0 < K; k0 += 32) {
        {
            const unsigned short* src = Bpack + (size_t)srow * K + k0 + shalf;
            short8 b0 = *(const short8*)(src);
            short8 b1 = *(const short8*)(src + 8);
            *(short8*)(&Bs[srow * LDT + shalf])     = b0;
            *(short8*)(&Bs[srow * LDT + shalf + 8]) = b1;
        }
        {
            int grow = row0 + srow;
            short8 a0 = zed, a1 = zed;
            if (AFP32) {
                if (grow < N_NODES) {
                    const float* src = (const float*)Ap + (size_t)grow * K + k0 + shalf;
                    float4v f0 = *(const float4v*)(src);
                    float4v f1 = *(const float4v*)(src + 4);
                    float4v f2 = *(const float4v*)(src + 8);
                    float4v f3 = *(const float4v*)(src + 12);
                    unsigned short t[16];
#pragma unroll
                    for (int j = 0; j < 4; ++j) t[j]      = f2bf(f0[j]);
#pragma unroll
                    for (int j = 0; j < 4; ++j) t[4 + j]  = f2bf(f1[j]);
#pragma unroll
                    for (int j = 0; j < 4; ++j) t[8 + j]  = f2bf(f2[j]);
#pragma unroll
                    for (int j = 0; j < 4; ++j) t[12 + j] = f2bf(f3[j]);
#pragma unroll
                    for (int j = 0; j < 8; ++j) a0[j] = (short)t[j];
#pragma unroll
                    for (int j = 0; j < 8; ++j) a1[j] = (short)t[8 + j];
                }
            } else {
                if (grow < N_NODES) {
                    const unsigned short* src = (const unsigned short*)Ap + (size_t)grow * K + k0 + shalf;
                    a0 = *(const short8*)(src);
                    a1 = *(const short8*)(src + 8);
                }
            }
            *(short8*)(&As[srow * LDT + shalf])     = a0;
            *(short8*)(&As[srow * LDT + shalf + 8]) = a1;
        }
        __syncthreads();

        short8 af[4], bfr[4];
#pragma unroll
        for (int mt = 0; mt < 4; ++mt)
            af[mt] = *(const short8*)(&As[(wrow + mt * 16 + c) * LDT + q * 8]);
#pragma unroll
        for (int nt = 0; nt < 4; ++nt)
            bfr[nt] = *(const short8*)(&Bs[(wcol + nt * 16 + c) * LDT + q * 8]);
#pragma unroll
        for (int mt = 0; mt < 4; ++mt)
#pragma unroll
            for (int nt = 0; nt < 4; ++nt)
                acc[mt][nt] = __builtin_amdgcn_mfma_f32_16x16x32_bf16(af[mt], bfr[nt], acc[mt][nt], 0, 0, 0);
        __syncthreads();
    }

    // epilogue. D: col = lane&15, row = q*4 + reg
#pragma unroll
    for (int mt = 0; mt < 4; ++mt) {
#pragma unroll
        for (int i = 0; i < 4; ++i) {
            int row = row0 + wrow + mt * 16 + q * 4 + i;
            if (row >= N_NODES) continue;
#pragma unroll
            for (int nt = 0; nt < 4; ++nt) {
                int cc = wcol + nt * 16 + c;
                float v = acc[mt][nt][i];
                if (MODE == 0) {
                    ((unsigned short*)outp)[(size_t)row * 128 + cc] = f2bf(v);
                } else {
                    float* o = (float*)outp;
                    if (cc < 64) o[(size_t)row * 64 + cc] = v + bias0[cc];
                    else o[(size_t)N_NODES * 64 + (size_t)row * 64 + (cc - 64)] = v + bias1[cc - 64];
                }
            }
        }
    }
}

// ---------------- CSR aggregation, latency-pipelined ----------------
// one wave per node; lane l handles channels {2l,2l+1}. Edge (src,weight) pairs are
// prefetched lane-parallel, broadcast via shfl, gathers 4-deep in flight.
template <bool RELU, bool BIAS>
__global__ __launch_bounds__(256) void k_agg(const unsigned int* __restrict__ in,
                                             unsigned int* __restrict__ out,
                                             const float* __restrict__ dinv,
                                             const int* __restrict__ esrc,
                                             const float* __restrict__ ew,
                                             const int* __restrict__ offs,
                                             const int* __restrict__ cnt,
                                             const float* __restrict__ bias) {
    int wid = (blockIdx.x * 256 + threadIdx.x) >> 6;
    if (wid >= N_NODES) return;
    int l = threadIdx.x & 63;
    float di = dinv[wid];
    unsigned int u = in[(size_t)wid * 64 + l];
    float vx = bf2f(u & 0xffffu), vy = bf2f(u >> 16);
    if (RELU) { vx = fmaxf(vx, 0.f); vy = fmaxf(vy, 0.f); }
    float sc = di * di;
    float ax = sc * vx, ay = sc * vy;
    if (BIAS) { ax += bias[2 * l]; ay += bias[2 * l + 1]; }
    int start = offs[wid];
    int n = cnt[wid];

    for (int base = 0; base < n; base += 64) {
        int m = min(n - base, 64);
        int sreg = 0; float wreg = 0.f;
        if (l < m) {
            sreg = esrc[start + base + l];
            wreg = ew[start + base + l];
        }
        int e = 0;
        for (; e + 4 <= m; e += 4) {
            int s0 = __shfl(sreg, e),     s1 = __shfl(sreg, e + 1);
            int s2 = __shfl(sreg, e + 2), s3 = __shfl(sreg, e + 3);
            float w0 = __shfl(wreg, e),     w1 = __shfl(wreg, e + 1);
            float w2 = __shfl(wreg, e + 2), w3 = __shfl(wreg, e + 3);
            unsigned int u0 = in[(size_t)s0 * 64 + l];
            unsigned int u1 = in[(size_t)s1 * 64 + l];
            unsigned int u2 = in[(size_t)s2 * 64 + l];
            unsigned int u3 = in[(size_t)s3 * 64 + l];
            float x0 = bf2f(u0 & 0xffffu), y0 = bf2f(u0 >> 16);
            float x1 = bf2f(u1 & 0xffffu), y1 = bf2f(u1 >> 16);
            float x2 = bf2f(u2 & 0xffffu), y2 = bf2f(u2 >> 16);
            float x3 = bf2f(u3 & 0xffffu), y3 = bf2f(u3 >> 16);
            if (RELU) {
                x0 = fmaxf(x0, 0.f); y0 = fmaxf(y0, 0.f);
                x1 = fmaxf(x1, 0.f); y1 = fmaxf(y1, 0.f);
                x2 = fmaxf(x2, 0.f); y2 = fmaxf(y2, 0.f);
                x3 = fmaxf(x3, 0.f); y3 = fmaxf(y3, 0.f);
            }
            ax += w0 * x0; ay += w0 * y0;
            ax += w1 * x1; ay += w1 * y1;
            ax += w2 * x2; ay += w2 * y2;
            ax += w3 * x3; ay += w3 * y3;
        }
        for (; e < m; ++e) {
            int s0 = __shfl(sreg, e);
            float w0 = __shfl(wreg, e);
            unsigned int u0 = in[(size_t)s0 * 64 + l];
            float x0 = bf2f(u0 & 0xffffu), y0 = bf2f(u0 >> 16);
            if (RELU) { x0 = fmaxf(x0, 0.f); y0 = fmaxf(y0, 0.f); }
            ax += w0 * x0; ay += w0 * y0;
        }
    }
    out[(size_t)wid * 64 + l] = (unsigned int)f2bf(ax) | ((unsigned int)f2bf(ay) << 16);
}

// ---------------- launch ----------------
extern "C" void kernel_launch(void* const* d_in, const int* in_sizes, int n_in,
                              void* d_out, int out_size, void* d_ws, size_t ws_size,
                              hipStream_t stream) {
    const float* x    = (const float*)d_in[0];
    const int*   ei   = (const int*)d_in[1];
    const float* W1   = (const float*)d_in[2];
    const float* b1   = (const float*)d_in[3];
    const float* Wmu  = (const float*)d_in[4];
    const float* bmu  = (const float*)d_in[5];
    const float* Wlv  = (const float*)d_in[6];
    const float* blv  = (const float*)d_in[7];
    float* outp = (float*)d_out;

    const int* src = ei;
    const int* dst = ei + E_EDGES;

    char* ws = (char*)d_ws;
    int*            hist   = (int*)(ws + WS_HIST);
    int*            cursor = (int*)(ws + WS_CURSOR);
    int*            offs   = (int*)(ws + WS_OFFS);
    float*          dinv   = (float*)(ws + WS_DINV);
    int*            bsums  = (int*)(ws + WS_BSUMS);
    int*            esrc   = (int*)(ws + WS_ESRC);
    float*          ew     = (float*)(ws + WS_EW);
    unsigned short* Wp1    = (unsigned short*)(ws + WS_WP1);
    unsigned short* Wp2    = (unsigned short*)(ws + WS_WP2);
    unsigned short* h0     = (unsigned short*)(ws + WS_H0);
    unsigned short* h      = (unsigned short*)(ws + WS_H);

    const int NB_N = (N_NODES + 255) / 256;
    const int NB_E = (E_EDGES + 255) / 256;
    const int NB_S = (N_NODES + 1023) / 1024;
    const int NB_G = (N_NODES + 127) / 128;

    k_init<<<NB_N, 256, 0, stream>>>(hist, cursor);
    k_hist<<<NB_E, 256, 0, stream>>>(dst, hist);
    k_dinv<<<NB_N, 256, 0, stream>>>(hist, dinv);
    k_scan1<<<NB_S, 256, 0, stream>>>(hist, offs, bsums);
    k_scan2<<<1, 128, 0, stream>>>(bsums, NB_S);
    k_scan3<<<NB_N, 256, 0, stream>>>(offs, bsums);
    k_fill<<<NB_E, 256, 0, stream>>>(src, dst, offs, cursor, dinv, esrc, ew);
    k_pack<<<128, 256, 0, stream>>>(W1, Wmu, Wlv, Wp1, Wp2);

    // layer 1: h0 = bf16(x) @ W1 (MFMA) ; h = A_hat h0 + b1
    k_mgemm<256, 1, 0><<<NB_G, 256, 0, stream>>>(x, Wp1, nullptr, nullptr, h0);
    k_agg<false, true><<<(N_NODES * 64 + 255) / 256, 256, 0, stream>>>(
        (const unsigned int*)h0, (unsigned int*)h, dinv, esrc, ew, offs, hist, b1);

    // layer 2+3: g = A_hat relu(h) ; [mu|logvar] = g @ [Wmu|Wlv] + bias
    k_agg<true, false><<<(N_NODES * 64 + 255) / 256, 256, 0, stream>>>(
        (const unsigned int*)h, (unsigned int*)h0, dinv, esrc, ew, offs, hist, nullptr);
    k_mgemm<128, 0, 1><<<NB_G, 256, 0, stream>>>(h0, Wp2, bmu, blv, outp);
}